// Round 7
// baseline (1105.124 us; speedup 1.0000x reference)
//
#include <hip/hip_runtime.h>
#include <hip/hip_cooperative_groups.h>

namespace cg = cooperative_groups;

#define H 512
#define NNODES 10000
#define NEDGES 160000
#define NLAYERS 5
#define NTILES 632  // (10000/128 ceil = 79) * (512/64 = 8)

typedef __attribute__((ext_vector_type(8))) short short8;
typedef __attribute__((ext_vector_type(4))) float floatx4;

// ---------- helpers ----------
__device__ inline unsigned short f2bf(float v) {
    union { float f; unsigned int u; } x; x.f = v;
    unsigned int r = (x.u + 0x7fffu + ((x.u >> 16) & 1u)) >> 16;
    return (unsigned short)r;
}
__device__ inline float bf2f(unsigned short u) {
    union { unsigned int u; float f; } x; x.u = ((unsigned int)u) << 16; return x.f;
}
__device__ inline void gl_lds16(const void* g, void* l) {
    __builtin_amdgcn_global_load_lds((const __attribute__((address_space(1))) void*)g,
                                     (__attribute__((address_space(3))) void*)l, 16, 0, 0);
}

// ---------- prep kernels ----------
__global__ void zero_int(int* __restrict__ p, int n) {
    int i = blockIdx.x * blockDim.x + threadIdx.x;
    if (i < n) p[i] = 0;
}

__global__ void cvt_f32_bf16(const float* __restrict__ in, unsigned short* __restrict__ out, int n4) {
    int i = blockIdx.x * blockDim.x + threadIdx.x;
    if (i < n4) {
        float4 v = ((const float4*)in)[i];
        ushort4 o;
        o.x = f2bf(v.x); o.y = f2bf(v.y); o.z = f2bf(v.z); o.w = f2bf(v.w);
        ((ushort4*)out)[i] = o;
    }
}

// batched: z in [0,6): 5 layer weights + vw1. out[n][k] = in[k][n], bf16
__global__ void transpose_cvt6(const float* __restrict__ Wg, const float* __restrict__ vw1,
                               unsigned short* __restrict__ Wt) {
    __shared__ float tile[32][33];
    const int z = blockIdx.z;
    const float* in = (z < NLAYERS) ? (Wg + (size_t)z * H * H) : vw1;
    unsigned short* out = Wt + (size_t)z * H * H;
    const int bx = blockIdx.x * 32;
    const int by = blockIdx.y * 32;
    const int tx = threadIdx.x, ty = threadIdx.y;  // (32,8)
    for (int i = ty; i < 32; i += 8)
        tile[i][tx] = in[(size_t)(by + i) * H + bx + tx];
    __syncthreads();
    for (int i = ty; i < 32; i += 8)
        out[(size_t)(bx + i) * H + by + tx] = f2bf(tile[tx][i]);
}

__global__ void edge_hist(const int* __restrict__ rows, int* __restrict__ counts, int n) {
    int i = blockIdx.x * blockDim.x + threadIdx.x;
    if (i < n) atomicAdd(&counts[rows[i]], 1);
}

__global__ __launch_bounds__(1024)
void scan_rows(const int* __restrict__ counts, int* __restrict__ row_ptr, int n) {
    __shared__ int sums[1024];
    const int t = threadIdx.x;
    const int base = t * 16;
    int local[16];
    int s = 0;
#pragma unroll
    for (int i = 0; i < 16; ++i) {
        int idx = base + i;
        int v = (idx < n) ? counts[idx] : 0;
        local[i] = s;
        s += v;
    }
    sums[t] = s;
    __syncthreads();
    for (int off = 1; off < 1024; off <<= 1) {
        int v = (t >= off) ? sums[t - off] : 0;
        __syncthreads();
        sums[t] += v;
        __syncthreads();
    }
    const int prefix = (t == 0) ? 0 : sums[t - 1];
#pragma unroll
    for (int i = 0; i < 16; ++i) {
        int idx = base + i;
        if (idx < n) row_ptr[idx] = prefix + local[i];
    }
    if (t == 0) row_ptr[n] = sums[1023];
}

__global__ void edge_scatter(const int* __restrict__ rows, const int* __restrict__ colsin,
                             const float* __restrict__ valsin, const int* __restrict__ row_ptr,
                             int* __restrict__ fill, int* __restrict__ colsout,
                             float* __restrict__ valsout, int n) {
    int i = blockIdx.x * blockDim.x + threadIdx.x;
    if (i < n) {
        int r = rows[i];
        int pos = row_ptr[r] + atomicAdd(&fill[r], 1);
        colsout[pos] = colsin[i];
        valsout[pos] = valsin[i];
    }
}

// ---------- r3-proven GEMM tile body (128x64, BK=64, XOR k-slot swizzle) ----------
__device__ __forceinline__ void gemm_tile_body(
    const unsigned short* __restrict__ A, const unsigned short* __restrict__ Bt,
    unsigned short* __restrict__ C, const float* __restrict__ bias,
    int has_bias_relu, int M, int tileM, int tileN,
    unsigned short* lsA, unsigned short* lsB) {
    const int t = threadIdx.x;
    const int lane = t & 63;
    const int wave = t >> 6;
    const int wm = wave >> 1, wn = wave & 1;
    const int quad = lane >> 4, r16 = lane & 15;

    floatx4 acc[4][2] = {};

    const unsigned short* ap[4];
#pragma unroll
    for (int q = 0; q < 4; ++q) {
        const int c = t + 256 * q;
        const int row = c >> 3;
        int g = tileM + row; if (g >= M) g = M - 1;
        ap[q] = A + (size_t)g * 512 + (((c & 7) ^ (row & 7)) * 8);
    }
    const unsigned short* bp[2];
#pragma unroll
    for (int q = 0; q < 2; ++q) {
        const int c = t + 256 * q;
        const int row = c >> 3;
        bp[q] = Bt + (size_t)(tileN + row) * 512 + (((c & 7) ^ (row & 7)) * 8);
    }

    for (int k0 = 0; k0 < 512; k0 += 64) {
        gl_lds16(ap[0] + k0, lsA + (size_t)t * 8);
        gl_lds16(ap[1] + k0, lsA + (size_t)(t + 256) * 8);
        gl_lds16(ap[2] + k0, lsA + (size_t)(t + 512) * 8);
        gl_lds16(ap[3] + k0, lsA + (size_t)(t + 768) * 8);
        gl_lds16(bp[0] + k0, lsB + (size_t)t * 8);
        gl_lds16(bp[1] + k0, lsB + (size_t)(t + 256) * 8);
        __syncthreads();

        short8 af[4][2], bfr[2][2];
#pragma unroll
        for (int i = 0; i < 4; ++i) {
            const int row = wm * 64 + i * 16 + r16;
#pragma unroll
            for (int kk = 0; kk < 2; ++kk) {
                const int kcw = kk * 4 + quad;
                af[i][kk] = *(const short8*)&lsA[(size_t)(row * 8 + (kcw ^ (row & 7))) * 8];
            }
        }
#pragma unroll
        for (int j = 0; j < 2; ++j) {
            const int row = wn * 32 + j * 16 + r16;
#pragma unroll
            for (int kk = 0; kk < 2; ++kk) {
                const int kcw = kk * 4 + quad;
                bfr[j][kk] = *(const short8*)&lsB[(size_t)(row * 8 + (kcw ^ (row & 7))) * 8];
            }
        }
#pragma unroll
        for (int kk = 0; kk < 2; ++kk)  // K ascending -> numerics match r3 exactly
#pragma unroll
            for (int i = 0; i < 4; ++i)
#pragma unroll
                for (int j = 0; j < 2; ++j)
                    acc[i][j] = __builtin_amdgcn_mfma_f32_16x16x32_bf16(af[i][kk], bfr[j][kk], acc[i][j], 0, 0, 0);
        __syncthreads();
    }

#pragma unroll
    for (int i = 0; i < 4; ++i) {
#pragma unroll
        for (int j = 0; j < 2; ++j) {
            const int col = tileN + wn * 32 + j * 16 + r16;
#pragma unroll
            for (int reg = 0; reg < 4; ++reg) {
                const int row = tileM + wm * 64 + i * 16 + quad * 4 + reg;
                if (row < M) {
                    float v = acc[i][j][reg];
                    if (has_bias_relu) { v += bias[col]; v = fmaxf(v, 0.f); }
                    C[(size_t)row * 512 + col] = f2bf(v);
                }
            }
        }
    }
}

// ---------- per-row SpMM body (r2/r3-proven) ----------
__device__ __forceinline__ void spmm_row(
    const int* __restrict__ row_ptr, const int* __restrict__ cols,
    const float* __restrict__ vals, const unsigned short* __restrict__ hmat,
    const float* __restrict__ bias, unsigned short* __restrict__ xout,
    int r, int lane) {
    const int s = row_ptr[r], e = row_ptr[r + 1];
    const int cb = lane * 8;
    float acc[8] = {0.f, 0.f, 0.f, 0.f, 0.f, 0.f, 0.f, 0.f};

    int i = s;
    for (; i + 8 <= e; i += 8) {
        int c[8]; float v[8]; short8 g[8];
#pragma unroll
        for (int u = 0; u < 8; ++u) { c[u] = cols[i + u]; v[u] = vals[i + u]; }
#pragma unroll
        for (int u = 0; u < 8; ++u) g[u] = *(const short8*)(hmat + (size_t)c[u] * H + cb);
#pragma unroll
        for (int u = 0; u < 8; ++u)
#pragma unroll
            for (int j = 0; j < 8; ++j) acc[j] += v[u] * bf2f((unsigned short)g[u][j]);
    }
    for (; i + 2 <= e; i += 2) {
        const int c0 = cols[i], c1 = cols[i + 1];
        const float v0 = vals[i], v1 = vals[i + 1];
        short8 g0 = *(const short8*)(hmat + (size_t)c0 * H + cb);
        short8 g1 = *(const short8*)(hmat + (size_t)c1 * H + cb);
#pragma unroll
        for (int j = 0; j < 8; ++j) acc[j] += v0 * bf2f((unsigned short)g0[j]);
#pragma unroll
        for (int j = 0; j < 8; ++j) acc[j] += v1 * bf2f((unsigned short)g1[j]);
    }
    if (i < e) {
        const int c = cols[i];
        const float v = vals[i];
        short8 g = *(const short8*)(hmat + (size_t)c * H + cb);
#pragma unroll
        for (int j = 0; j < 8; ++j) acc[j] += v * bf2f((unsigned short)g[j]);
    }

    short8 o;
#pragma unroll
    for (int j = 0; j < 8; ++j)
        o[j] = (short)f2bf(fmaxf(acc[j] + bias[cb + j], 0.f));
    *(short8*)(xout + (size_t)r * H + cb) = o;
}

__device__ __forceinline__ void head_row(
    const unsigned short* __restrict__ h2, const float* __restrict__ w2,
    const float* __restrict__ b2, float* __restrict__ out, int r, int lane) {
    const unsigned short* hrow = h2 + (size_t)r * H;
    float acc = 0.f;
#pragma unroll
    for (int i = 0; i < 8; ++i) {
        const int c = lane * 8 + i;
        acc += bf2f(hrow[c]) * w2[c];
    }
#pragma unroll
    for (int off = 32; off >= 1; off >>= 1) acc += __shfl_xor(acc, off, 64);
    if (lane == 0) out[r] = 1.f / (1.f + expf(-(acc + b2[0])));
}

// ---------- fused cooperative kernel: 6 GEMM + 5 SpMM + head, work-stealing ----------
__global__ __launch_bounds__(256)
void fused_main(unsigned short* x, unsigned short* h,
                const unsigned short* Wt, const float* bg, const float* vb1,
                const float* vw2, const float* vb2,
                const int* row_ptr, const int* cols, const float* vals,
                int* ctrs, float* out) {
    cg::grid_group grid = cg::this_grid();
    __shared__ __align__(16) unsigned short lsA[128 * 64];  // 16 KB
    __shared__ __align__(16) unsigned short lsB[64 * 64];   //  8 KB
    __shared__ int s_work;
    const int t = threadIdx.x;
    const int wave = t >> 6, lane = t & 63;

    for (int l = 0; l < NLAYERS; ++l) {
        // GEMM layer l: h = x @ Wt[l]^T (tiles stolen dynamically)
        for (;;) {
            __syncthreads();
            if (t == 0) s_work = atomicAdd(&ctrs[2 * l], 1);
            __syncthreads();
            const int id = s_work;
            if (id >= NTILES) break;
            gemm_tile_body(x, Wt + (size_t)l * H * H, h, nullptr, 0, NNODES,
                           (id >> 3) * 128, (id & 7) * 64, lsA, lsB);
        }
        grid.sync();
        // SpMM layer l: x = relu(S*h + bg[l])  (8 rows per steal, 2 per wave)
        for (;;) {
            __syncthreads();
            if (t == 0) s_work = atomicAdd(&ctrs[2 * l + 1], 1);
            __syncthreads();
            const int base = s_work * 8;
            if (base >= NNODES) break;
#pragma unroll
            for (int rr = 0; rr < 2; ++rr) {
                const int r = base + wave * 2 + rr;
                if (r < NNODES)
                    spmm_row(row_ptr, cols, vals, h, bg + (size_t)l * H, x, r, lane);
            }
        }
        grid.sync();
    }
    // final GEMM: h = relu(x @ vw1^T + vb1)
    for (;;) {
        __syncthreads();
        if (t == 0) s_work = atomicAdd(&ctrs[10], 1);
        __syncthreads();
        const int id = s_work;
        if (id >= NTILES) break;
        gemm_tile_body(x, Wt + (size_t)NLAYERS * H * H, h, vb1, 1, NNODES,
                       (id >> 3) * 128, (id & 7) * 64, lsA, lsB);
    }
    grid.sync();
    // head (16 rows per steal, 4 per wave)
    for (;;) {
        __syncthreads();
        if (t == 0) s_work = atomicAdd(&ctrs[11], 1);
        __syncthreads();
        const int base = s_work * 16;
        if (base >= NNODES) break;
#pragma unroll
        for (int rr = 0; rr < 4; ++rr) {
            const int r = base + wave * 4 + rr;
            if (r < NNODES) head_row(h, vw2, vb2, out, r, lane);
        }
    }
}

// ---------- standalone fallback kernels (r3 path, if coop launch unsupported) ----------
__global__ __launch_bounds__(256)
void gemm_bf16_bt(const unsigned short* __restrict__ A, const unsigned short* __restrict__ Bt,
                  unsigned short* __restrict__ C, const float* __restrict__ bias,
                  int has_bias_relu, int M) {
    __shared__ __align__(16) unsigned short lsA[128 * 64];
    __shared__ __align__(16) unsigned short lsB[64 * 64];
    gemm_tile_body(A, Bt, C, bias, has_bias_relu, M,
                   blockIdx.x * 128, blockIdx.y * 64, lsA, lsB);
}

__global__ __launch_bounds__(256)
void spmm_bias_relu(const int* __restrict__ row_ptr, const int* __restrict__ cols,
                    const float* __restrict__ vals, const unsigned short* __restrict__ hmat,
                    const float* __restrict__ bias, unsigned short* __restrict__ xout) {
    const int wave = threadIdx.x >> 6, lane = threadIdx.x & 63;
    const int r = blockIdx.x * 4 + wave;
    if (r >= NNODES) return;
    spmm_row(row_ptr, cols, vals, hmat, bias, xout, r, lane);
}

__global__ __launch_bounds__(256)
void final_head(const unsigned short* __restrict__ h2, const float* __restrict__ w2,
                const float* __restrict__ b2, float* __restrict__ out, int n) {
    const int wave = threadIdx.x >> 6, lane = threadIdx.x & 63;
    const int r = blockIdx.x * 4 + wave;
    if (r >= n) return;
    head_row(h2, w2, b2, out, r, lane);
}

extern "C" void kernel_launch(void* const* d_in, const int* in_sizes, int n_in,
                              void* d_out, int out_size, void* d_ws, size_t ws_size,
                              hipStream_t stream) {
    (void)in_sizes; (void)n_in; (void)out_size; (void)ws_size;
    const float* feat   = (const float*)d_in[0];
    const int* adj_row  = (const int*)d_in[1];
    const int* adj_col  = (const int*)d_in[2];
    const float* adj_val= (const float*)d_in[3];
    const float* Wg     = (const float*)d_in[4];
    const float* bg     = (const float*)d_in[5];
    const float* vw1    = (const float*)d_in[6];
    const float* vb1    = (const float*)d_in[7];
    const float* vw2    = (const float*)d_in[8];
    const float* vb2    = (const float*)d_in[9];
    float* out = (float*)d_out;

    // workspace layout (bytes)
    char* ws = (char*)d_ws;
    unsigned short* x  = (unsigned short*)(ws + 0);          // 10,240,000
    unsigned short* h  = (unsigned short*)(ws + 10240000);   // 10,240,000
    unsigned short* Wt = (unsigned short*)(ws + 20480000);   // 3,145,728
    int*   row_ptr = (int*)(ws + 23625728);                  // 40,960
    int*   counts  = (int*)(ws + 23666688);                  // 40,960
    int*   fill    = (int*)(ws + 23707648);                  // 40,960
    int*   ctrs    = (int*)(ws + 23748608);                  // 64 (12 phase counters)
    int*   colsS   = (int*)(ws + 23748672);                  // 640,000
    float* valsS   = (float*)(ws + 24388672);                // 640,000 -> ~25 MB

    // --- prep ---
    zero_int<<<(20496 + 255) / 256, 256, 0, stream>>>(counts, 20496);  // counts+fill+ctrs
    cvt_f32_bf16<<<(NNODES * H / 4 + 255) / 256, 256, 0, stream>>>(feat, x, NNODES * H / 4);
    transpose_cvt6<<<dim3(16, 16, 6), dim3(32, 8), 0, stream>>>(Wg, vw1, Wt);
    edge_hist<<<(NEDGES + 255) / 256, 256, 0, stream>>>(adj_row, counts, NEDGES);
    scan_rows<<<1, 1024, 0, stream>>>(counts, row_ptr, NNODES);
    edge_scatter<<<(NEDGES + 255) / 256, 256, 0, stream>>>(adj_row, adj_col, adj_val,
                                                           row_ptr, fill, colsS, valsS, NEDGES);

    // --- fused cooperative main (512 blocks = 2/CU guaranteed co-resident) ---
    void* args[] = {(void*)&x, (void*)&h, (void*)&Wt, (void*)&bg, (void*)&vb1,
                    (void*)&vw2, (void*)&vb2, (void*)&row_ptr, (void*)&colsS,
                    (void*)&valsS, (void*)&ctrs, (void*)&out};
    hipError_t err = hipLaunchCooperativeKernel((const void*)fused_main,
                                                dim3(512), dim3(256), args, 0, stream);
    if (err != hipSuccess) {
        // fallback: r3-style dispatch sequence (identical math)
        dim3 gg((NNODES + 127) / 128, 8);
        for (int l = 0; l < NLAYERS; ++l) {
            gemm_bf16_bt<<<gg, 256, 0, stream>>>(x, Wt + (size_t)l * H * H, h, nullptr, 0, NNODES);
            spmm_bias_relu<<<(NNODES + 3) / 4, 256, 0, stream>>>(row_ptr, colsS, valsS, h,
                                                                 bg + (size_t)l * H, x);
        }
        gemm_bf16_bt<<<gg, 256, 0, stream>>>(x, Wt + (size_t)NLAYERS * H * H, h, vb1, 1, NNODES);
        final_head<<<(NNODES + 3) / 4, 256, 0, stream>>>(h, vw2, vb2, out, NNODES);
    }
}

// Round 8
// 325.285 us; speedup vs baseline: 3.3974x; 3.3974x over previous
//
#include <hip/hip_runtime.h>

#define H 512
#define NNODES 10000
#define NEDGES 160000
#define NLAYERS 5

typedef __attribute__((ext_vector_type(8))) short short8;
typedef __attribute__((ext_vector_type(4))) float floatx4;

// ---------- helpers ----------
__device__ inline unsigned short f2bf(float v) {
    union { float f; unsigned int u; } x; x.f = v;
    unsigned int r = (x.u + 0x7fffu + ((x.u >> 16) & 1u)) >> 16;
    return (unsigned short)r;
}
__device__ inline float bf2f(unsigned short u) {
    union { unsigned int u; float f; } x; x.u = ((unsigned int)u) << 16; return x.f;
}
__device__ inline void gl_lds16(const void* g, void* l) {
    __builtin_amdgcn_global_load_lds((const __attribute__((address_space(1))) void*)g,
                                     (__attribute__((address_space(3))) void*)l, 16, 0, 0);
}

// ---------- prep kernels ----------
__global__ void zero_int(int* __restrict__ p, int n) {
    int i = blockIdx.x * blockDim.x + threadIdx.x;
    if (i < n) p[i] = 0;
}

__global__ void cvt_f32_bf16(const float* __restrict__ in, unsigned short* __restrict__ out, int n4) {
    int i = blockIdx.x * blockDim.x + threadIdx.x;
    if (i < n4) {
        float4 v = ((const float4*)in)[i];
        ushort4 o;
        o.x = f2bf(v.x); o.y = f2bf(v.y); o.z = f2bf(v.z); o.w = f2bf(v.w);
        ((ushort4*)out)[i] = o;
    }
}

// batched: z in [0,6): 5 layer weights + vw1. out[n][k] = in[k][n], bf16
__global__ void transpose_cvt6(const float* __restrict__ Wg, const float* __restrict__ vw1,
                               unsigned short* __restrict__ Wt) {
    __shared__ float tile[32][33];
    const int z = blockIdx.z;
    const float* in = (z < NLAYERS) ? (Wg + (size_t)z * H * H) : vw1;
    unsigned short* out = Wt + (size_t)z * H * H;
    const int bx = blockIdx.x * 32;
    const int by = blockIdx.y * 32;
    const int tx = threadIdx.x, ty = threadIdx.y;  // (32,8)
    for (int i = ty; i < 32; i += 8)
        tile[i][tx] = in[(size_t)(by + i) * H + bx + tx];
    __syncthreads();
    for (int i = ty; i < 32; i += 8)
        out[(size_t)(bx + i) * H + by + tx] = f2bf(tile[tx][i]);
}

__global__ void edge_hist(const int* __restrict__ rows, int* __restrict__ counts, int n) {
    int i = blockIdx.x * blockDim.x + threadIdx.x;
    if (i < n) atomicAdd(&counts[rows[i]], 1);
}

// prefix-sum of row counts PADDED to multiples of 8 (dummy edges have val=0
// -> exact no-ops in the accumulation; enables branch-free SpMM rounds)
__global__ __launch_bounds__(1024)
void scan_rows_pad(const int* __restrict__ counts, int* __restrict__ row_ptr, int n) {
    __shared__ int sums[1024];
    const int t = threadIdx.x;
    const int base = t * 16;
    int local[16];
    int s = 0;
#pragma unroll
    for (int i = 0; i < 16; ++i) {
        int idx = base + i;
        int v = (idx < n) ? ((counts[idx] + 7) & ~7) : 0;
        local[i] = s;
        s += v;
    }
    sums[t] = s;
    __syncthreads();
    for (int off = 1; off < 1024; off <<= 1) {
        int v = (t >= off) ? sums[t - off] : 0;
        __syncthreads();
        sums[t] += v;
        __syncthreads();
    }
    const int prefix = (t == 0) ? 0 : sums[t - 1];
#pragma unroll
    for (int i = 0; i < 16; ++i) {
        int idx = base + i;
        if (idx < n) row_ptr[idx] = prefix + local[i];
    }
    if (t == 0) row_ptr[n] = sums[1023];
}

__global__ void edge_scatter(const int* __restrict__ rows, const int* __restrict__ colsin,
                             const float* __restrict__ valsin, const int* __restrict__ row_ptr,
                             int* __restrict__ fill, int* __restrict__ colsout,
                             float* __restrict__ valsout, int n) {
    int i = blockIdx.x * blockDim.x + threadIdx.x;
    if (i < n) {
        int r = rows[i];
        int pos = row_ptr[r] + atomicAdd(&fill[r], 1);
        colsout[pos] = colsin[i];
        valsout[pos] = valsin[i];
    }
}

// ---------- r3-proven GEMM body (128x64, BK=64, XOR k-slot swizzle) ----------
__device__ __forceinline__ void gemm_tile_body(
    const unsigned short* __restrict__ A, const unsigned short* __restrict__ Bt,
    unsigned short* __restrict__ C, const float* __restrict__ bias,
    int has_bias_relu, int M, int tileM, int tileN,
    unsigned short* lsA, unsigned short* lsB) {
    const int t = threadIdx.x;
    const int lane = t & 63;
    const int wave = t >> 6;
    const int wm = wave >> 1, wn = wave & 1;
    const int quad = lane >> 4, r16 = lane & 15;

    floatx4 acc[4][2] = {};

    const unsigned short* ap[4];
#pragma unroll
    for (int q = 0; q < 4; ++q) {
        const int c = t + 256 * q;
        const int row = c >> 3;
        int g = tileM + row; if (g >= M) g = M - 1;
        ap[q] = A + (size_t)g * 512 + (((c & 7) ^ (row & 7)) * 8);
    }
    const unsigned short* bp[2];
#pragma unroll
    for (int q = 0; q < 2; ++q) {
        const int c = t + 256 * q;
        const int row = c >> 3;
        bp[q] = Bt + (size_t)(tileN + row) * 512 + (((c & 7) ^ (row & 7)) * 8);
    }

    for (int k0 = 0; k0 < 512; k0 += 64) {
        gl_lds16(ap[0] + k0, lsA + (size_t)t * 8);
        gl_lds16(ap[1] + k0, lsA + (size_t)(t + 256) * 8);
        gl_lds16(ap[2] + k0, lsA + (size_t)(t + 512) * 8);
        gl_lds16(ap[3] + k0, lsA + (size_t)(t + 768) * 8);
        gl_lds16(bp[0] + k0, lsB + (size_t)t * 8);
        gl_lds16(bp[1] + k0, lsB + (size_t)(t + 256) * 8);
        __syncthreads();

        short8 af[4][2], bfr[2][2];
#pragma unroll
        for (int i = 0; i < 4; ++i) {
            const int row = wm * 64 + i * 16 + r16;
#pragma unroll
            for (int kk = 0; kk < 2; ++kk) {
                const int kcw = kk * 4 + quad;
                af[i][kk] = *(const short8*)&lsA[(size_t)(row * 8 + (kcw ^ (row & 7))) * 8];
            }
        }
#pragma unroll
        for (int j = 0; j < 2; ++j) {
            const int row = wn * 32 + j * 16 + r16;
#pragma unroll
            for (int kk = 0; kk < 2; ++kk) {
                const int kcw = kk * 4 + quad;
                bfr[j][kk] = *(const short8*)&lsB[(size_t)(row * 8 + (kcw ^ (row & 7))) * 8];
            }
        }
#pragma unroll
        for (int kk = 0; kk < 2; ++kk)  // K ascending -> numerics match r3 exactly
#pragma unroll
            for (int i = 0; i < 4; ++i)
#pragma unroll
                for (int j = 0; j < 2; ++j)
                    acc[i][j] = __builtin_amdgcn_mfma_f32_16x16x32_bf16(af[i][kk], bfr[j][kk], acc[i][j], 0, 0, 0);
        __syncthreads();
    }

#pragma unroll
    for (int i = 0; i < 4; ++i) {
#pragma unroll
        for (int j = 0; j < 2; ++j) {
            const int col = tileN + wn * 32 + j * 16 + r16;
#pragma unroll
            for (int reg = 0; reg < 4; ++reg) {
                const int row = tileM + wm * 64 + i * 16 + quad * 4 + reg;
                if (row < M) {
                    float v = acc[i][j][reg];
                    if (has_bias_relu) { v += bias[col]; v = fmaxf(v, 0.f); }
                    C[(size_t)row * 512 + col] = f2bf(v);
                }
            }
        }
    }
}

// XCD-aware launch wrapper: grid = 640 linear blocks. Decode so that all 8
// N-slices of one M-tile share (L % 8) -> same XCD (round-robin dispatch
// heuristic) -> A-tile lands in that XCD's L2 once, reused 8x. If the %8
// mapping assumption is wrong this is neutral, never incorrect.
__global__ __launch_bounds__(256)
void gemm_bf16_xcd(const unsigned short* __restrict__ A, const unsigned short* __restrict__ Bt,
                   unsigned short* __restrict__ C, const float* __restrict__ bias,
                   int has_bias_relu, int M) {
    __shared__ __align__(16) unsigned short lsA[128 * 64];  // 16 KB
    __shared__ __align__(16) unsigned short lsB[64 * 64];   //  8 KB
    const int L = blockIdx.x;
    const int m_low = L & 7;
    const int rest = L >> 3;         // 0..79
    const int n = rest & 7;          // 0..7
    const int m_high = rest >> 3;    // 0..9
    const int m = m_high * 8 + m_low;  // 0..79
    gemm_tile_body(A, Bt, C, bias, has_bias_relu, M, m * 128, n * 64, lsA, lsB);
}

// ---------- SpMM + bias + relu on padded CSR: branch-free unroll-8 rounds ----------
__global__ __launch_bounds__(256)
void spmm_pad(const int* __restrict__ prow, const int* __restrict__ cols,
              const float* __restrict__ vals, const unsigned short* __restrict__ hmat,
              const float* __restrict__ bias, unsigned short* __restrict__ xout) {
    const int wave = threadIdx.x >> 6, lane = threadIdx.x & 63;
    const int r = blockIdx.x * 4 + wave;
    if (r >= NNODES) return;
    const int s = prow[r], e = prow[r + 1];  // length is a multiple of 8
    const int cb = lane * 8;
    float acc[8] = {0.f, 0.f, 0.f, 0.f, 0.f, 0.f, 0.f, 0.f};

    for (int i = s; i < e; i += 8) {
        int c[8]; float v[8]; short8 g[8];
#pragma unroll
        for (int u = 0; u < 8; ++u) { c[u] = cols[i + u]; v[u] = vals[i + u]; }
#pragma unroll
        for (int u = 0; u < 8; ++u) g[u] = *(const short8*)(hmat + (size_t)c[u] * H + cb);
#pragma unroll
        for (int u = 0; u < 8; ++u)  // real-edge order preserved; pads are exact +0
#pragma unroll
            for (int j = 0; j < 8; ++j) acc[j] += v[u] * bf2f((unsigned short)g[u][j]);
    }

    short8 o;
#pragma unroll
    for (int j = 0; j < 8; ++j)
        o[j] = (short)f2bf(fmaxf(acc[j] + bias[cb + j], 0.f));
    *(short8*)(xout + (size_t)r * H + cb) = o;
}

// ---------- head: out[r] = sigmoid(dot(h2[r,:], w2) + b2) ----------
__global__ __launch_bounds__(256)
void final_head(const unsigned short* __restrict__ h2, const float* __restrict__ w2,
                const float* __restrict__ b2, float* __restrict__ out, int n) {
    const int wave = threadIdx.x >> 6, lane = threadIdx.x & 63;
    const int r = blockIdx.x * 4 + wave;
    if (r >= n) return;
    const unsigned short* hrow = h2 + (size_t)r * H;
    float acc = 0.f;
#pragma unroll
    for (int i = 0; i < 8; ++i) {
        const int c = lane * 8 + i;
        acc += bf2f(hrow[c]) * w2[c];
    }
#pragma unroll
    for (int off = 32; off >= 1; off >>= 1) acc += __shfl_xor(acc, off, 64);
    if (lane == 0) out[r] = 1.f / (1.f + expf(-(acc + b2[0])));
}

extern "C" void kernel_launch(void* const* d_in, const int* in_sizes, int n_in,
                              void* d_out, int out_size, void* d_ws, size_t ws_size,
                              hipStream_t stream) {
    (void)in_sizes; (void)n_in; (void)out_size; (void)ws_size;
    const float* feat   = (const float*)d_in[0];
    const int* adj_row  = (const int*)d_in[1];
    const int* adj_col  = (const int*)d_in[2];
    const float* adj_val= (const float*)d_in[3];
    const float* Wg     = (const float*)d_in[4];
    const float* bg     = (const float*)d_in[5];
    const float* vw1    = (const float*)d_in[6];
    const float* vb1    = (const float*)d_in[7];
    const float* vw2    = (const float*)d_in[8];
    const float* vb2    = (const float*)d_in[9];
    float* out = (float*)d_out;

    // workspace layout (bytes)
    char* ws = (char*)d_ws;
    unsigned short* x  = (unsigned short*)(ws + 0);          // 10,240,000
    unsigned short* h  = (unsigned short*)(ws + 10240000);   // 10,240,000
    unsigned short* Wt = (unsigned short*)(ws + 20480000);   // 3,145,728
    int*   prow    = (int*)(ws + 23625728);                  // 160,064
    int*   counts  = (int*)(ws + 23785792);                  // 40,000
    int*   fill    = (int*)(ws + 23825792);                  // 40,000 (contiguous after counts)
    int*   colsP   = (int*)(ws + 23865792);                  // 960,000 (240k padded edges)
    float* valsP   = (float*)(ws + 24825792);                // 960,000 -> ~25.8 MB

    // --- prep ---
    zero_int<<<(20000 + 255) / 256, 256, 0, stream>>>(counts, 20000);          // counts + fill
    zero_int<<<(480000 + 255) / 256, 256, 0, stream>>>(colsP, 480000);         // colsP + valsP (pad slots)
    cvt_f32_bf16<<<(NNODES * H / 4 + 255) / 256, 256, 0, stream>>>(feat, x, NNODES * H / 4);
    transpose_cvt6<<<dim3(16, 16, 6), dim3(32, 8), 0, stream>>>(Wg, vw1, Wt);
    edge_hist<<<(NEDGES + 255) / 256, 256, 0, stream>>>(adj_row, counts, NEDGES);
    scan_rows_pad<<<1, 1024, 0, stream>>>(counts, prow, NNODES);
    edge_scatter<<<(NEDGES + 255) / 256, 256, 0, stream>>>(adj_row, adj_col, adj_val,
                                                           prow, fill, colsP, valsP, NEDGES);

    // --- layers ---
    for (int l = 0; l < NLAYERS; ++l) {
        gemm_bf16_xcd<<<640, 256, 0, stream>>>(x, Wt + (size_t)l * H * H, h, nullptr, 0, NNODES);
        spmm_pad<<<(NNODES + 3) / 4, 256, 0, stream>>>(prow, colsP, valsP, h, bg + (size_t)l * H, x);
    }
    gemm_bf16_xcd<<<640, 256, 0, stream>>>(x, Wt + (size_t)NLAYERS * H * H, h, vb1, 1, NNODES);
    final_head<<<(NNODES + 3) / 4, 256, 0, stream>>>(h, vw2, vb2, out, NNODES);
}